// Round 16
// baseline (68.283 us; speedup 1.0000x reference)
//
#include <hip/hip_runtime.h>
#include <hip/hip_fp16.h>

#define IN_DIM  16384
#define OUT_DIM 16384
#define BATCH   2048
#define TPB     512
#define ITS     (OUT_DIM / (TPB * 8))   // 4 j-iterations (8 columns each)
#define CHK     (IN_DIM / (TPB * 8))    // 4 stage chunks of 8 floats per thread

typedef float f32x4 __attribute__((ext_vector_type(4)));

// Two half2's per output column: ab = (c0, c1), cd = (c2, c3). 8 bytes.
struct h2x2 { __half2 ab, cd; };

// OP_COEFFS from the reference, row-major [16][4]
__device__ __constant__ float OPC[16][4] = {
    {0.f, 0.f, 0.f, 0.f}, {0.f, 0.f, 0.f, 1.f}, {0.f, 1.f, 0.f, -1.f}, {0.f, 1.f, 0.f, 0.f},
    {0.f, 0.f, 1.f, -1.f}, {0.f, 0.f, 1.f, 0.f}, {0.f, 1.f, 1.f, -2.f}, {0.f, 1.f, 1.f, -1.f},
    {1.f, -1.f, -1.f, 1.f}, {1.f, -1.f, -1.f, 2.f}, {1.f, 0.f, -1.f, 0.f}, {1.f, 0.f, -1.f, 1.f},
    {1.f, -1.f, 0.f, 0.f}, {1.f, -1.f, 0.f, 1.f}, {1.f, 0.f, 0.f, -1.f}, {1.f, 0.f, 0.f, 0.f}};

// Prep: coef (f16x4) + packed f16-LDS byte offsets: (idx_a*2) | (idx_b*2)<<16.
__global__ __launch_bounds__(256) void prep_kernel(const float* __restrict__ w,
                                                   const int* __restrict__ ia,
                                                   const int* __restrict__ ib,
                                                   h2x2* __restrict__ coefh,
                                                   unsigned* __restrict__ packed) {
    int j = blockIdx.x * 256 + threadIdx.x;
    if (j >= OUT_DIM) return;

    const float4* wr = (const float4*)(w + (size_t)j * 16);
    float wv[16];
    float4 w0 = wr[0], w1 = wr[1], w2 = wr[2], w3 = wr[3];
    wv[0] = w0.x; wv[1] = w0.y; wv[2] = w0.z; wv[3] = w0.w;
    wv[4] = w1.x; wv[5] = w1.y; wv[6] = w1.z; wv[7] = w1.w;
    wv[8] = w2.x; wv[9] = w2.y; wv[10] = w2.z; wv[11] = w2.w;
    wv[12] = w3.x; wv[13] = w3.y; wv[14] = w3.z; wv[15] = w3.w;

    float m = wv[0];
#pragma unroll
    for (int k = 1; k < 16; ++k) m = fmaxf(m, wv[k]);
    float s = 0.f;
#pragma unroll
    for (int k = 0; k < 16; ++k) { wv[k] = expf(wv[k] - m); s += wv[k]; }
    float inv = 1.f / s;

    float c0 = 0.f, c1 = 0.f, c2 = 0.f, c3 = 0.f;
#pragma unroll
    for (int k = 0; k < 16; ++k) {
        float p = wv[k];
        c0 = fmaf(p, OPC[k][0], c0);
        c1 = fmaf(p, OPC[k][1], c1);
        c2 = fmaf(p, OPC[k][2], c2);
        c3 = fmaf(p, OPC[k][3], c3);
    }
    h2x2 c;
    c.ab = __floats2half2_rn(c0 * inv, c1 * inv);
    c.cd = __floats2half2_rn(c2 * inv, c3 * inv);
    coefh[j] = c;
    packed[j] = ((unsigned)ia[j] << 1) | ((unsigned)ib[j] << 17);
}

__device__ __forceinline__ unsigned pack2(float a, float b) {
    return __builtin_bit_cast(unsigned, __builtin_amdgcn_cvt_pkrtz(a, b));
}

// Wide-gather single-shot: one row/block, 32 KiB f16 LDS, 8 columns per
// thread per iteration -> 16 independent ds_read_u16 in flight per wave per
// iteration (2x latency amortization vs R12), two coalesced float4 stores.
// NO sched_barrier in the loop: the fully-unrolled iterations are free to
// interleave (R12-R15 diagnosis: exposed per-iteration LDS latency behind a
// scheduling wall, not any saturated pipe, is the 56us plateau).
// (512,2) -> 128-VGPR cap; demand ~90 -> no spill.
__global__ __launch_bounds__(TPB, 2) void logic_kernel(const float* __restrict__ x,
                                                       const unsigned* __restrict__ packed,
                                                       const h2x2* __restrict__ coefh,
                                                       float* __restrict__ out) {
    __shared__ __half lds[IN_DIM];  // 32 KiB

    const int tid = threadIdx.x;
    const size_t row = blockIdx.x;

    // Stage: 8 float4 loads, pack f32->f16, 4 x 16B ds_write.
    {
        const float4* s4 = (const float4*)(x + row * IN_DIM);
        uint4 tt[CHK];
#pragma unroll
        for (int c = 0; c < CHK; ++c) {
            float4 v0 = s4[(c * TPB + tid) * 2 + 0];
            float4 v1 = s4[(c * TPB + tid) * 2 + 1];
            tt[c].x = pack2(v0.x, v0.y); tt[c].y = pack2(v0.z, v0.w);
            tt[c].z = pack2(v1.x, v1.y); tt[c].w = pack2(v1.z, v1.w);
        }
#pragma unroll
        for (int c = 0; c < CHK; ++c)
            *(uint4*)((char*)lds + (size_t)(c * TPB + tid) * 16) = tt[c];
    }

    // Prefetch iteration 0's pi/cf while the stage drains at the barrier.
    uint4 p0 = *(const uint4*)(packed + tid * 8);
    uint4 p1 = *(const uint4*)(packed + tid * 8 + 4);
    h2x2 cf[8];
#pragma unroll
    for (int k = 0; k < 8; ++k) cf[k] = coefh[tid * 8 + k];

    __syncthreads();

    const char* bufc = (const char*)lds;
    float* outr = out + row * IN_DIM;

#pragma unroll
    for (int it = 0; it < ITS; ++it) {
        const int j0 = (it * TPB + tid) * 8;

        // Snapshot current, then prefetch next (loads fly under this
        // iteration's gather + FMA + store; no sched_barrier wall).
        const uint4 q0 = p0, q1 = p1;
        h2x2 cc[8];
#pragma unroll
        for (int k = 0; k < 8; ++k) cc[k] = cf[k];

        if (it + 1 < ITS) {
            const int jn = ((it + 1) * TPB + tid) * 8;
            p0 = *(const uint4*)(packed + jn);
            p1 = *(const uint4*)(packed + jn + 4);
#pragma unroll
            for (int k = 0; k < 8; ++k) cf[k] = coefh[jn + k];
        }

        f32x4 oL, oH;
#define COL(P, CF, OV, FLD)                                                         \
        {                                                                           \
            float a = __half2float(*(const __half*)(bufc + ((P) & 0xFFFFu)));       \
            float b = __half2float(*(const __half*)(bufc + ((P) >> 16)));           \
            float c0 = __low2float((CF).ab), c1 = __high2float((CF).ab);            \
            float c2 = __low2float((CF).cd), c3 = __high2float((CF).cd);            \
            OV.FLD = fmaf(a, fmaf(c3, b, c1), fmaf(c2, b, c0));                     \
        }
        COL(q0.x, cc[0], oL, x)
        COL(q0.y, cc[1], oL, y)
        COL(q0.z, cc[2], oL, z)
        COL(q0.w, cc[3], oL, w)
        COL(q1.x, cc[4], oH, x)
        COL(q1.y, cc[5], oH, y)
        COL(q1.z, cc[6], oH, z)
        COL(q1.w, cc[7], oH, w)
#undef COL
        *(f32x4*)(outr + j0) = oL;
        *(f32x4*)(outr + j0 + 4) = oH;
    }
}

extern "C" void kernel_launch(void* const* d_in, const int* in_sizes, int n_in,
                              void* d_out, int out_size, void* d_ws, size_t ws_size,
                              hipStream_t stream) {
    const float* x = (const float*)d_in[0];
    const int* ia = (const int*)d_in[1];
    const int* ib = (const int*)d_in[2];
    const float* w = (const float*)d_in[3];
    float* out = (float*)d_out;

    // ws layout: [0, 128 KiB) coefh h2x2[OUT_DIM]; [128 KiB, 192 KiB) packed u32[OUT_DIM]
    h2x2* coefh = (h2x2*)d_ws;
    unsigned* packed = (unsigned*)((char*)d_ws + (size_t)OUT_DIM * sizeof(h2x2));

    prep_kernel<<<OUT_DIM / 256, 256, 0, stream>>>(w, ia, ib, coefh, packed);
    logic_kernel<<<BATCH, TPB, 0, stream>>>(x, packed, coefh, out);
}

// Round 17
// 50.260 us; speedup vs baseline: 1.3586x; 1.3586x over previous
//
#include <hip/hip_runtime.h>
#include <hip/hip_fp16.h>

#define IN_DIM  16384
#define OUT_DIM 16384
#define BATCH   2048
#define TPB     512
#define ITS     (OUT_DIM / (TPB * 4))   // 8 j-iterations (4 columns each)
#define CHK     (IN_DIM / (TPB * 8))    // 4 stage chunks of 8 floats per thread

typedef float f32x4 __attribute__((ext_vector_type(4)));

// Two half2's per output column: ab = (c0, c1), cd = (c2, c3). 8 bytes.
struct h2x2 { __half2 ab, cd; };

// OP_COEFFS from the reference, row-major [16][4]
__device__ __constant__ float OPC[16][4] = {
    {0.f, 0.f, 0.f, 0.f}, {0.f, 0.f, 0.f, 1.f}, {0.f, 1.f, 0.f, -1.f}, {0.f, 1.f, 0.f, 0.f},
    {0.f, 0.f, 1.f, -1.f}, {0.f, 0.f, 1.f, 0.f}, {0.f, 1.f, 1.f, -2.f}, {0.f, 1.f, 1.f, -1.f},
    {1.f, -1.f, -1.f, 1.f}, {1.f, -1.f, -1.f, 2.f}, {1.f, 0.f, -1.f, 0.f}, {1.f, 0.f, -1.f, 1.f},
    {1.f, -1.f, 0.f, 0.f}, {1.f, -1.f, 0.f, 1.f}, {1.f, 0.f, 0.f, -1.f}, {1.f, 0.f, 0.f, 0.f}};

// Prep: coef (f16x4) + packed f16-LDS byte offsets: (idx_a*2) | (idx_b*2)<<16.
__global__ __launch_bounds__(256) void prep_kernel(const float* __restrict__ w,
                                                   const int* __restrict__ ia,
                                                   const int* __restrict__ ib,
                                                   h2x2* __restrict__ coefh,
                                                   unsigned* __restrict__ packed) {
    int j = blockIdx.x * 256 + threadIdx.x;
    if (j >= OUT_DIM) return;

    const float4* wr = (const float4*)(w + (size_t)j * 16);
    float wv[16];
    float4 w0 = wr[0], w1 = wr[1], w2 = wr[2], w3 = wr[3];
    wv[0] = w0.x; wv[1] = w0.y; wv[2] = w0.z; wv[3] = w0.w;
    wv[4] = w1.x; wv[5] = w1.y; wv[6] = w1.z; wv[7] = w1.w;
    wv[8] = w2.x; wv[9] = w2.y; wv[10] = w2.z; wv[11] = w2.w;
    wv[12] = w3.x; wv[13] = w3.y; wv[14] = w3.z; wv[15] = w3.w;

    float m = wv[0];
#pragma unroll
    for (int k = 1; k < 16; ++k) m = fmaxf(m, wv[k]);
    float s = 0.f;
#pragma unroll
    for (int k = 0; k < 16; ++k) { wv[k] = expf(wv[k] - m); s += wv[k]; }
    float inv = 1.f / s;

    float c0 = 0.f, c1 = 0.f, c2 = 0.f, c3 = 0.f;
#pragma unroll
    for (int k = 0; k < 16; ++k) {
        float p = wv[k];
        c0 = fmaf(p, OPC[k][0], c0);
        c1 = fmaf(p, OPC[k][1], c1);
        c2 = fmaf(p, OPC[k][2], c2);
        c3 = fmaf(p, OPC[k][3], c3);
    }
    h2x2 c;
    c.ab = __floats2half2_rn(c0 * inv, c1 * inv);
    c.cd = __floats2half2_rn(c2 * inv, c3 * inv);
    coefh[j] = c;
    packed[j] = ((unsigned)ia[j] << 1) | ((unsigned)ib[j] << 17);
}

__device__ __forceinline__ unsigned pack2(float a, float b) {
    return __builtin_bit_cast(unsigned, __builtin_amdgcn_cvt_pkrtz(a, b));
}

// R12 structure (best: 55.7us) with ONE change: nontemporal out-stores.
// Diagnosis: per replay, out (128 MiB, write-allocate) cycles through the
// 256 MiB L3 and evicts half of x -> FETCH_SIZE ~67 MB of HBM re-reads and
// read/write contention at HBM during every stage phase. NT stores bypass
// L3 allocation: x stays L3-resident, stage waits become L3-latency, net
// HBM bytes drop ~197 -> ~150 MB. Everything else identical to R12.
__global__ __launch_bounds__(TPB, 4) void logic_kernel(const float* __restrict__ x,
                                                       const unsigned* __restrict__ packed,
                                                       const h2x2* __restrict__ coefh,
                                                       float* __restrict__ out) {
    __shared__ __half lds[IN_DIM];  // 32 KiB

    const int tid = threadIdx.x;
    const size_t row = blockIdx.x;

    // Stage: 8 float4 loads, pack f32->f16, ds_write.
    {
        const float4* s4 = (const float4*)(x + row * IN_DIM);
        uint4 tt[CHK];
#pragma unroll
        for (int c = 0; c < CHK; ++c) {
            float4 v0 = s4[(c * TPB + tid) * 2 + 0];
            float4 v1 = s4[(c * TPB + tid) * 2 + 1];
            tt[c].x = pack2(v0.x, v0.y); tt[c].y = pack2(v0.z, v0.w);
            tt[c].z = pack2(v1.x, v1.y); tt[c].w = pack2(v1.z, v1.w);
        }
#pragma unroll
        for (int c = 0; c < CHK; ++c)
            *(uint4*)((char*)lds + (size_t)(c * TPB + tid) * 16) = tt[c];
    }

    // Prefetch iteration 0's pi/cf while waiting on the barrier.
    uint4 pi = *(const uint4*)(packed + tid * 4);
    h2x2 cA = coefh[tid * 4 + 0];
    h2x2 cB = coefh[tid * 4 + 1];
    h2x2 cC = coefh[tid * 4 + 2];
    h2x2 cD = coefh[tid * 4 + 3];

    __syncthreads();

    const char* bufc = (const char*)lds;
    float* outr = out + row * IN_DIM;

#pragma unroll
    for (int it = 0; it < ITS; ++it) {
        // Issue next iteration's loads first; they fly under this iteration's
        // gather + FMA + store.
        uint4 pin = pi;
        h2x2 nA = cA, nB = cB, nC = cC, nD = cD;
        if (it + 1 < ITS) {
            const int jn = ((it + 1) * TPB + tid) * 4;
            pin = *(const uint4*)(packed + jn);
            nA = coefh[jn + 0];
            nB = coefh[jn + 1];
            nC = coefh[jn + 2];
            nD = coefh[jn + 3];
        }
        __builtin_amdgcn_sched_barrier(0);  // keep prefetch issue ahead of compute

        const int j0 = (it * TPB + tid) * 4;
        f32x4 o;
#define COL(P, CF, FLD)                                                             \
        {                                                                           \
            float a = __half2float(*(const __half*)(bufc + ((P) & 0xFFFFu)));       \
            float b = __half2float(*(const __half*)(bufc + ((P) >> 16)));           \
            float c0 = __low2float(CF.ab), c1 = __high2float(CF.ab);                \
            float c2 = __low2float(CF.cd), c3 = __high2float(CF.cd);                \
            o.FLD = fmaf(a, fmaf(c3, b, c1), fmaf(c2, b, c0));                      \
        }
        COL(pi.x, cA, x)
        COL(pi.y, cB, y)
        COL(pi.z, cC, z)
        COL(pi.w, cD, w)
#undef COL
        __builtin_nontemporal_store(o, (f32x4*)(outr + j0));

        pi = pin; cA = nA; cB = nB; cC = nC; cD = nD;
    }
}

extern "C" void kernel_launch(void* const* d_in, const int* in_sizes, int n_in,
                              void* d_out, int out_size, void* d_ws, size_t ws_size,
                              hipStream_t stream) {
    const float* x = (const float*)d_in[0];
    const int* ia = (const int*)d_in[1];
    const int* ib = (const int*)d_in[2];
    const float* w = (const float*)d_in[3];
    float* out = (float*)d_out;

    // ws layout: [0, 128 KiB) coefh h2x2[OUT_DIM]; [128 KiB, 192 KiB) packed u32[OUT_DIM]
    h2x2* coefh = (h2x2*)d_ws;
    unsigned* packed = (unsigned*)((char*)d_ws + (size_t)OUT_DIM * sizeof(h2x2));

    prep_kernel<<<OUT_DIM / 256, 256, 0, stream>>>(w, ia, ib, coefh, packed);
    logic_kernel<<<BATCH, TPB, 0, stream>>>(x, packed, coefh, out);
}